// Round 5
// baseline (177.772 us; speedup 1.0000x reference)
//
#include <hip/hip_runtime.h>
#include <hip/hip_cooperative_groups.h>

namespace cg = cooperative_groups;

// Problem constants (fixed by setup_inputs)
#define T_   16
#define TOK_ 16384
#define P_   8192
#define N_   32768
#define D_   128
#define L_   8
#define C_   16

typedef float f32x4 __attribute__((ext_vector_type(4)));

constexpr int NBLOCKS      = 1024;   // 4 blocks/CU * 256 CUs -> all co-resident
constexpr int BLOCKS_PER_T = 64;     // 64 blocks per timestamp
constexpr int ROWS_PER_BLK = 128;    // 8192 rows / 64 blocks

// ---------------------------------------------------------------------------
// One cooperative kernel, three phases:
//  A) gather x rows at node_pos, LN(D=128), pool 8->1 fused algebraically,
//     per-group-l accumulate -> partial[block][128]   (proven R4 structure)
//  -- grid.sync() --
//  B) every block redundantly reduces its t's 64 partial chunks and applies
//     LN(128, g_fin/b_fin) then per-16 LN (g_dec/b_dec) -> dec[128] in LDS
//  C) block streams its 256KB output slice: t=b>>6, rows [s*512,(s+1)*512),
//     constant l=s>>3, per-thread-constant value, plain f32x4 stores.
// ---------------------------------------------------------------------------
__global__ __launch_bounds__(256, 4) void fused_all(
    const float* __restrict__ x,
    const float* __restrict__ g_enc, const float* __restrict__ b_enc,
    const float* __restrict__ g_fin, const float* __restrict__ b_fin,
    const float* __restrict__ g_dec, const float* __restrict__ b_dec,
    const int* __restrict__ node_pos, const int* __restrict__ node_ids,
    float* __restrict__ partial, float* __restrict__ out)
{
    __shared__ float lds[4 * 128];
    __shared__ float dec[128];
    const int tid   = threadIdx.x;
    const int lane  = tid & 63;
    const int wid   = tid >> 6;
    const int j     = lane & 15;   // pooled channel / sublane
    const int q     = lane >> 4;   // quarter (row within 4-row batch)
    const int b     = blockIdx.x;
    const int t     = b >> 6;
    const int chunk = b & 63;
    const int tP    = t * P_;
    const float* xt = x + (size_t)t * TOK_ * D_;

    // ---------------- Phase A: gather + LN + pool + group-accumulate -------
    {
        // per-lane LN params for elements d = 8j..8j+7
        const f32x4 g0  = *(const f32x4*)(g_enc + 8 * j);
        const f32x4 g1  = *(const f32x4*)(g_enc + 8 * j + 4);
        const f32x4 bb0 = *(const f32x4*)(b_enc + 8 * j);
        const f32x4 bb1 = *(const f32x4*)(b_enc + 8 * j + 4);
        const float G = g0.x + g0.y + g0.z + g0.w + g1.x + g1.y + g1.z + g1.w;
        const float B = bb0.x + bb0.y + bb0.z + bb0.w + bb1.x + bb1.y + bb1.z + bb1.w;

        float acc[L_];
#pragma unroll
        for (int ll = 0; ll < L_; ++ll) acc[ll] = 0.f;

#pragma unroll
        for (int pass = 0; pass < 2; ++pass) {
            const int pbase = chunk * ROWS_PER_BLK + pass * 64 + wid * 16;
            // lanes 0..15 hold this pass's 16 row indices (others duplicate)
            const int posv = node_pos[tP + pbase + j];
            const int nidv = node_ids[tP + pbase + j];

            // issue ALL 8 gather loads up-front (row r=i*4+q, d=8j..8j+7)
            f32x4 va[4], vb[4];
#pragma unroll
            for (int i = 0; i < 4; ++i) {
                const int p = __shfl(posv, i * 4 + q);
                const float* row = xt + (size_t)p * D_ + 8 * j;
                va[i] = *(const f32x4*)(row);
                vb[i] = *(const f32x4*)(row + 4);
            }
#pragma unroll
            for (int i = 0; i < 4; ++i) {
                const f32x4 a = va[i], c = vb[i];
                float s  = a.x + a.y + a.z + a.w + c.x + c.y + c.z + c.w;
                float ss = a.x*a.x + a.y*a.y + a.z*a.z + a.w*a.w
                         + c.x*c.x + c.y*c.y + c.z*c.z + c.w*c.w;
                float dot = a.x*g0.x + a.y*g0.y + a.z*g0.z + a.w*g0.w
                          + c.x*g1.x + c.y*g1.y + c.z*g1.z + c.w*g1.w;
#pragma unroll
                for (int m = 1; m < 16; m <<= 1) {
                    s  += __shfl_xor(s, m);
                    ss += __shfl_xor(ss, m);
                }
                const float mean = s * (1.f / 128.f);
                const float rstd = rsqrtf(ss * (1.f / 128.f) - mean * mean + 1e-5f);
                const float srow = (dot - mean * G) * rstd + B;
                const int l = __shfl(nidv, i * 4 + q) >> 12;
#pragma unroll
                for (int ll = 0; ll < L_; ++ll) acc[ll] += (ll == l) ? srow : 0.f;
            }
        }

        // combine quarters (lanes j, j+16, j+32, j+48 share channel j)
#pragma unroll
        for (int ll = 0; ll < L_; ++ll) {
            acc[ll] += __shfl_xor(acc[ll], 16);
            acc[ll] += __shfl_xor(acc[ll], 32);
        }
        if (lane < 16) {
#pragma unroll
            for (int ll = 0; ll < L_; ++ll) lds[wid * 128 + ll * 16 + j] = acc[ll];
        }
        __syncthreads();
        if (tid < 128) {
            const float sum = lds[tid] + lds[128 + tid] + lds[256 + tid] + lds[384 + tid];
            partial[(size_t)b * 128 + tid] = sum;
        }
    }

    cg::this_grid().sync();

    // ---------------- Phase B: redundant per-block finalize of own t -------
    {
        const float* pb = partial + (size_t)t * BLOCKS_PER_T * 128;
        float a0 = 0.f, a1 = 0.f;
        const int k0 = wid * 16;
#pragma unroll 4
        for (int k = 0; k < 16; ++k) {
            a0 += pb[(k0 + k) * 128 + lane];
            a1 += pb[(k0 + k) * 128 + 64 + lane];
        }
        lds[wid * 128 + lane]      = a0;
        lds[wid * 128 + 64 + lane] = a1;
        __syncthreads();
        if (wid == 0) {
            float c0 = (lds[lane] + lds[128 + lane] + lds[256 + lane] + lds[384 + lane])
                       * (1.f / 32768.f);
            float c1 = (lds[64 + lane] + lds[192 + lane] + lds[320 + lane] + lds[448 + lane])
                       * (1.f / 32768.f);
            float s = c0 + c1, ss = c0 * c0 + c1 * c1;
#pragma unroll
            for (int m = 1; m < 64; m <<= 1) {
                s  += __shfl_xor(s, m);
                ss += __shfl_xor(ss, m);
            }
            const float mean = s * (1.f / 128.f);
            const float rstd = rsqrtf(ss * (1.f / 128.f) - mean * mean + 1e-5f);
            const float e0 = (c0 - mean) * rstd * g_fin[lane]      + b_fin[lane];
            const float e1 = (c1 - mean) * rstd * g_fin[lane + 64] + b_fin[lane + 64];

            float s0 = e0, q0 = e0 * e0, s1 = e1, q1 = e1 * e1;
#pragma unroll
            for (int m = 1; m < 16; m <<= 1) {
                s0 += __shfl_xor(s0, m); q0 += __shfl_xor(q0, m);
                s1 += __shfl_xor(s1, m); q1 += __shfl_xor(q1, m);
            }
            const float m0 = s0 * (1.f / 16.f), m1 = s1 * (1.f / 16.f);
            const float r0 = rsqrtf(q0 * (1.f / 16.f) - m0 * m0 + 1e-5f);
            const float r1 = rsqrtf(q1 * (1.f / 16.f) - m1 * m1 + 1e-5f);
            const int c = lane & 15;
            const float gd = g_dec[c], bd = b_dec[c];
            dec[lane]      = (e0 - m0) * r0 * gd + bd;
            dec[64 + lane] = (e1 - m1) * r1 * gd + bd;
        }
        __syncthreads();
    }

    // ---------------- Phase C: stream 256 KB output slice ------------------
    {
        const int s = chunk;                       // slice: rows [s*512,(s+1)*512)
        const float val = dec[((s >> 3) << 4) + ((tid & 31) >> 1)];
        const f32x4 v4 = {val, val, val, val};
        f32x4* p = (f32x4*)out + (((size_t)t << 20) + ((size_t)s << 14) + tid);
#pragma unroll
        for (int it = 0; it < 64; ++it)
            p[it * 256] = v4;
    }
}

extern "C" void kernel_launch(void* const* d_in, const int* in_sizes, int n_in,
                              void* d_out, int out_size, void* d_ws, size_t ws_size,
                              hipStream_t stream)
{
    const float* x      = (const float*)d_in[0];
    const float* g_enc  = (const float*)d_in[1];
    const float* b_enc  = (const float*)d_in[2];
    const float* g_fin  = (const float*)d_in[3];
    const float* b_fin  = (const float*)d_in[4];
    const float* g_dec  = (const float*)d_in[5];
    const float* b_dec  = (const float*)d_in[6];
    const int*   node_pos = (const int*)d_in[7];
    const int*   node_ids = (const int*)d_in[8];

    float* partial = (float*)d_ws;        // 1024*128 f32 = 512 KB
    float* out     = (float*)d_out;

    void* args[] = {
        (void*)&x, (void*)&g_enc, (void*)&b_enc, (void*)&g_fin, (void*)&b_fin,
        (void*)&g_dec, (void*)&b_dec, (void*)&node_pos, (void*)&node_ids,
        (void*)&partial, (void*)&out
    };
    hipLaunchCooperativeKernel((const void*)fused_all, dim3(NBLOCKS), dim3(256),
                               args, 0, stream);
}

// Round 6
// 81.112 us; speedup vs baseline: 2.1917x; 2.1917x over previous
//
#include <hip/hip_runtime.h>

// Problem constants (fixed by setup_inputs)
#define T_   16
#define TOK_ 16384
#define P_   8192
#define N_   32768
#define D_   128
#define L_   8
#define C_   16

typedef float f32x2 __attribute__((ext_vector_type(2)));
typedef float f32x4 __attribute__((ext_vector_type(4)));

constexpr int K1_BLOCKS     = 2048;
constexpr int BLOCKS_PER_T  = 128;   // K1 producer blocks per timestamp
constexpr int ROWS_PER_WAVE = 16;    // 8192 rows / (128 blocks * 4 waves)

// ---------------------------------------------------------------------------
// Kernel 1: gather x rows at node_pos, LayerNorm over D=128 (g_enc,b_enc),
// pool 8->1, accumulate per group l = node_id>>12 into per-block partials.
// 16 lanes per row; all 8 gather loads per wave issue up-front; cached loads
// (x is L3-hot: R5 measured only ~35 MB HBM fetch for the whole pipeline).
// ---------------------------------------------------------------------------
__global__ __launch_bounds__(256) void k1_gather_ln_pool(
    const float* __restrict__ x,
    const float* __restrict__ g_enc, const float* __restrict__ b_enc,
    const int* __restrict__ node_pos, const int* __restrict__ node_ids,
    float* __restrict__ partial)
{
    __shared__ float lds[4 * 128];
    const int tid   = threadIdx.x;
    const int lane  = tid & 63;
    const int wid   = tid >> 6;
    const int j     = lane & 15;   // channel
    const int q     = lane >> 4;   // quarter (row within batch)
    const int b     = blockIdx.x;
    const int t     = b >> 7;      // 128 blocks per t
    const int chunk = b & 127;
    const int pbase = chunk * 64 + wid * ROWS_PER_WAVE;
    const int tP    = t * P_;
    const float* xt = x + (size_t)t * TOK_ * D_;

    // per-lane LN params for elements d = 8j..8j+7
    const f32x4 g0  = *(const f32x4*)(g_enc + 8 * j);
    const f32x4 g1  = *(const f32x4*)(g_enc + 8 * j + 4);
    const f32x4 bb0 = *(const f32x4*)(b_enc + 8 * j);
    const f32x4 bb1 = *(const f32x4*)(b_enc + 8 * j + 4);
    const float G = g0.x + g0.y + g0.z + g0.w + g1.x + g1.y + g1.z + g1.w;
    const float B = bb0.x + bb0.y + bb0.z + bb0.w + bb1.x + bb1.y + bb1.z + bb1.w;

    // lanes 0..15 hold the wave's 16 row indices (other lanes duplicate)
    const int posv = node_pos[tP + pbase + j];
    const int nidv = node_ids[tP + pbase + j];

    // issue ALL gather loads up-front: row r = i*4+q, lane reads d=8j..8j+7
    f32x4 va[4], vb[4];
#pragma unroll
    for (int i = 0; i < 4; ++i) {
        const int p = __shfl(posv, i * 4 + q);
        const float* row = xt + (size_t)p * D_ + 8 * j;
        va[i] = *(const f32x4*)(row);
        vb[i] = *(const f32x4*)(row + 4);
    }

    float acc[L_];
#pragma unroll
    for (int ll = 0; ll < L_; ++ll) acc[ll] = 0.f;

#pragma unroll
    for (int i = 0; i < 4; ++i) {
        const f32x4 a = va[i], c = vb[i];
        float s  = a.x + a.y + a.z + a.w + c.x + c.y + c.z + c.w;
        float ss = a.x*a.x + a.y*a.y + a.z*a.z + a.w*a.w
                 + c.x*c.x + c.y*c.y + c.z*c.z + c.w*c.w;
        float dot = a.x*g0.x + a.y*g0.y + a.z*g0.z + a.w*g0.w
                  + c.x*g1.x + c.y*g1.y + c.z*g1.z + c.w*g1.w;
        // LN stats over the row's 128 elements: reduce across 16 lanes
#pragma unroll
        for (int m = 1; m < 16; m <<= 1) {
            s  += __shfl_xor(s, m);
            ss += __shfl_xor(ss, m);
        }
        const float mean = s * (1.f / 128.f);
        const float rstd = rsqrtf(ss * (1.f / 128.f) - mean * mean + 1e-5f);
        const float srow = (dot - mean * G) * rstd + B;   // channel-c pooled sum
        const int l = __shfl(nidv, i * 4 + q) >> 12;
#pragma unroll
        for (int ll = 0; ll < L_; ++ll) acc[ll] += (ll == l) ? srow : 0.f;
    }

    // combine quarters (lanes j, j+16, j+32, j+48 share channel j)
#pragma unroll
    for (int ll = 0; ll < L_; ++ll) {
        acc[ll] += __shfl_xor(acc[ll], 16);
        acc[ll] += __shfl_xor(acc[ll], 32);
    }
    if (lane < 16) {
#pragma unroll
        for (int ll = 0; ll < L_; ++ll) lds[wid * 128 + ll * 16 + j] = acc[ll];
    }
    __syncthreads();
    if (tid < 128) {
        const float sum = lds[tid] + lds[128 + tid] + lds[256 + tid] + lds[384 + tid];
        partial[(size_t)b * 128 + tid] = sum;   // deterministic overwrite
    }
}

// ---------------------------------------------------------------------------
// Kernel 2: reduce 128 partials per t, scale, LN over 128 (g_fin,b_fin),
// LN over 16-element groups (g_dec,b_dec) -> decoded[t*128 + l*16 + c]
// ---------------------------------------------------------------------------
__global__ __launch_bounds__(64) void k2_finalize(
    const float* __restrict__ partial,
    const float* __restrict__ g_fin, const float* __restrict__ b_fin,
    const float* __restrict__ g_dec, const float* __restrict__ b_dec,
    float* __restrict__ decoded)
{
    const int t = blockIdx.x;
    const int lane = threadIdx.x;
    const float* pb = partial + (size_t)t * BLOCKS_PER_T * 128;
    float a0 = 0.f, a1 = 0.f;
#pragma unroll 8
    for (int k = 0; k < BLOCKS_PER_T; ++k) {
        a0 += pb[k * 128 + lane];
        a1 += pb[k * 128 + 64 + lane];
    }
    a0 *= (1.f / 32768.f);   // /4096 scatter slots /8 pooled
    a1 *= (1.f / 32768.f);

    float s = a0 + a1, ss = a0 * a0 + a1 * a1;
#pragma unroll
    for (int m = 1; m < 64; m <<= 1) {
        s  += __shfl_xor(s, m);
        ss += __shfl_xor(ss, m);
    }
    const float mean = s * (1.f / 128.f);
    const float rstd = rsqrtf(ss * (1.f / 128.f) - mean * mean + 1e-5f);
    const float c0 = (a0 - mean) * rstd * g_fin[lane]      + b_fin[lane];
    const float c1 = (a1 - mean) * rstd * g_fin[lane + 64] + b_fin[lane + 64];

    float s0 = c0, q0 = c0 * c0, s1 = c1, q1 = c1 * c1;
#pragma unroll
    for (int m = 1; m < 16; m <<= 1) {
        s0 += __shfl_xor(s0, m); q0 += __shfl_xor(q0, m);
        s1 += __shfl_xor(s1, m); q1 += __shfl_xor(q1, m);
    }
    const float m0 = s0 * (1.f / 16.f), m1 = s1 * (1.f / 16.f);
    const float r0 = rsqrtf(q0 * (1.f / 16.f) - m0 * m0 + 1e-5f);
    const float r1 = rsqrtf(q1 * (1.f / 16.f) - m1 * m1 + 1e-5f);
    const int c = lane & 15;
    const float gd = g_dec[c], bd = b_dec[c];
    decoded[t * 128 + lane]      = (c0 - m0) * r0 * gd + bd;
    decoded[t * 128 + 64 + lane] = (c1 - m1) * r1 * gd + bd;
}

// ---------------------------------------------------------------------------
// Kernel 3: out[t,n,d] = decoded[t, n>>12, d>>3].
// 2048 blocks; block b covers one contiguous 128 KB slice of one (t, l).
// Per-thread value is constant -> pure store stream. A/B this round:
// PLAIN stores (L2 write-combining path, like the 7 TB/s harness fills)
// instead of nontemporal.
// ---------------------------------------------------------------------------
__global__ __launch_bounds__(256) void k3_broadcast(
    const float* __restrict__ decoded, f32x4* __restrict__ out)
{
    const int tid   = threadIdx.x;
    const int b     = blockIdx.x;
    const int t     = b >> 7;
    const int chunk = b & 127;
    const int l     = chunk >> 4;                 // 16 blocks per l-group
    const float val = decoded[(t << 7) + (l << 4) + ((tid & 31) >> 1)];
    const f32x4 v4 = {val, val, val, val};
    f32x4* p = out + (((size_t)t << 20) + ((size_t)chunk << 13) + tid);
#pragma unroll
    for (int it = 0; it < 32; ++it)
        p[it << 8] = v4;                          // plain cached stores
}

extern "C" void kernel_launch(void* const* d_in, const int* in_sizes, int n_in,
                              void* d_out, int out_size, void* d_ws, size_t ws_size,
                              hipStream_t stream)
{
    const float* x      = (const float*)d_in[0];
    const float* g_enc  = (const float*)d_in[1];
    const float* b_enc  = (const float*)d_in[2];
    const float* g_fin  = (const float*)d_in[3];
    const float* b_fin  = (const float*)d_in[4];
    const float* g_dec  = (const float*)d_in[5];
    const float* b_dec  = (const float*)d_in[6];
    const int*   node_pos = (const int*)d_in[7];
    const int*   node_ids = (const int*)d_in[8];

    float* partial = (float*)d_ws;                         // 2048*128 f32 = 1 MB
    float* decoded = partial + (size_t)K1_BLOCKS * 128;    // 2048 f32
    float* out = (float*)d_out;

    hipLaunchKernelGGL(k1_gather_ln_pool, dim3(K1_BLOCKS), dim3(256), 0, stream,
                       x, g_enc, b_enc, node_pos, node_ids, partial);
    hipLaunchKernelGGL(k2_finalize, dim3(T_), dim3(64), 0, stream,
                       partial, g_fin, b_fin, g_dec, b_dec, decoded);
    hipLaunchKernelGGL(k3_broadcast, dim3(2048), dim3(256), 0, stream,
                       decoded, (f32x4*)out);
}